// Round 5
// baseline (201.107 us; speedup 1.0000x reference)
//
#include <hip/hip_runtime.h>

#define N_NODES 250000
#define N_EDGES 4000000
#define HID 32
#define NN 50
#define NF 3
#define OUT_COLS (NN + NF)   // 53

#define NB 512                                    // nodes per bucket
#define NBKT ((N_NODES + NB - 1) / NB)            // 489 buckets
#define CHUNK 8192                                // edges per partition block
#define NPBLK ((N_EDGES + CHUNK - 1) / CHUNK)     // 489
#define BCAP_SLOT 8832                            // bucket capacity (mean 8192 + 7 sigma)

typedef float float2v __attribute__((ext_vector_type(2)));

__device__ __forceinline__ float softplus_f(float v) {
    return fmaxf(v, 0.0f) + log1pf(expf(-fabsf(v)));
}

__device__ __forceinline__ float2v pk_fma(float a, float2v b, float2v c) {
    float2v av = {a, a};
    return __builtin_elementwise_fma(av, b, c);
}

// ---- P1: partition edges into fixed-capacity bucket regions ----
// record: w0 = col | (lrow<<18)  (col<2^18, lrow<2^9), w1 = attr bits
// DIRECT-SCATTER version: no LDS staging, no scan, no pass 3.
//  - 8 contiguous edges/thread -> int4/float4 loads (32B/lane, coalesced)
//  - pass-1 LDS histogram atomic returns the record's rank in its bucket
//  - store straight to bpay[gbase[b]+rank]; 8B scattered stores are merged
//    in L2 (byte-granular dirty tracking makes cross-block line sharing safe
//    -- the old bucket-contiguous writes already relied on this at run
//    boundaries). LDS: 80 KB -> 4 KB.
__global__ __launch_bounds__(1024, 8) void part_kernel(
    const int* __restrict__ ei, const float* __restrict__ ea,
    int* __restrict__ gcursor, int2* __restrict__ bpay)
{
    __shared__ int hist[NBKT];     // ~2 KB
    __shared__ int gbase[NBKT];    // ~2 KB

    int t = threadIdx.x;
    int cbb = blockIdx.x * CHUNK;
    int e0 = cbb + t * 8;

    for (int i = t; i < NBKT; i += 1024) hist[i] = 0;
    __syncthreads();

    // pass 1: vectorized row loads; histogram atomic RETURNS rank
    int r[8], rk[8];
    bool full = (e0 + 8 <= N_EDGES);
    if (full) {
        int4 ra = *(const int4*)(ei + e0);
        int4 rb = *(const int4*)(ei + e0 + 4);
        r[0] = ra.x; r[1] = ra.y; r[2] = ra.z; r[3] = ra.w;
        r[4] = rb.x; r[5] = rb.y; r[6] = rb.z; r[7] = rb.w;
    } else {
        #pragma unroll
        for (int j = 0; j < 8; j++) r[j] = (e0 + j < N_EDGES) ? ei[e0 + j] : 0;
    }
    #pragma unroll
    for (int j = 0; j < 8; j++)
        rk[j] = (e0 + j < N_EDGES) ? atomicAdd(&hist[r[j] >> 9], 1) : 0;
    __syncthreads();

    // per-bucket global base via one atomic per non-empty bucket
    for (int i = t; i < NBKT; i += 1024) {
        int h = hist[i];
        gbase[i] = i * BCAP_SLOT + (h > 0 ? atomicAdd(&gcursor[i], h) : 0);
    }
    __syncthreads();

    // pass 2: vectorized col/attr loads; direct scattered 8B stores
    int c[8]; float a[8];
    if (full) {
        int4 ca = *(const int4*)(ei + N_EDGES + e0);
        int4 cb = *(const int4*)(ei + N_EDGES + e0 + 4);
        float4 aa = *(const float4*)(ea + e0);
        float4 ab = *(const float4*)(ea + e0 + 4);
        c[0] = ca.x; c[1] = ca.y; c[2] = ca.z; c[3] = ca.w;
        c[4] = cb.x; c[5] = cb.y; c[6] = cb.z; c[7] = cb.w;
        a[0] = aa.x; a[1] = aa.y; a[2] = aa.z; a[3] = aa.w;
        a[4] = ab.x; a[5] = ab.y; a[6] = ab.z; a[7] = ab.w;
    } else {
        #pragma unroll
        for (int j = 0; j < 8; j++) {
            bool ok = (e0 + j < N_EDGES);
            c[j] = ok ? ei[N_EDGES + e0 + j] : 0;
            a[j] = ok ? ea[e0 + j] : 0.0f;
        }
    }
    #pragma unroll
    for (int j = 0; j < 8; j++) {
        if (e0 + j < N_EDGES) {
            int bb = r[j] >> 9;
            int lrow = r[j] & (NB - 1);
            int gpos = gbase[bb] + rk[j];
            if (gpos < (bb + 1) * BCAP_SLOT)   // overflow clamp (never in practice)
                bpay[gpos] = make_int2(c[j] | (lrow << 18), __float_as_int(a[j]));
        }
    }
}

// ---- P2+P3 fused: per-bucket counting sort into LDS + gather math ----
// 489 blocks x 512 threads; 1 thread per node. Sorted records never touch
// global memory. Phase A loads 2 records per int4 (guarded over-read lands
// in the ws scratch area past bpay -- safe by workspace layout). Phase C
// placement is atomic-free (rank from phase A's histogram atomic). Phase D
// is degree-sorted for wave-uniform edge counts. Epilogue folds W2 into
// Wc/Wmu/Wsig per block: (S@W2)·w == S·(W2@w).
// NOTE: no grid-wide spin barrier (round-3 post-mortem: 20 ms pathology).
__global__ __launch_bounds__(512, 4) void bucket_kernel(
    const int2* __restrict__ bpay, const int* __restrict__ gcursor,
    const float* __restrict__ x,
    const float* __restrict__ W1, const float* __restrict__ b1,
    const float* __restrict__ W2, const float* __restrict__ b2,
    const float* __restrict__ Wc, const float* __restrict__ bc,
    const float* __restrict__ Wmu, const float* __restrict__ bmu,
    const float* __restrict__ Wsig, const float* __restrict__ bsig,
    const float* __restrict__ high,
    float* __restrict__ sum_out, float* __restrict__ out)
{
    __shared__ int2 srec[BCAP_SLOT];   // 69 KB — node-sorted records
    __shared__ int hist[NB];           // 2 KB (per-node degree)
    __shared__ int nbeg[NB];           // 2 KB (per-node start, immutable)
    __shared__ int perm[NB];           // 2 KB (degree-sorted rank -> node)
    __shared__ int dhist[64];          // 256 B (degree bins -> cursor)
    __shared__ int wsum[8];
    __shared__ float bsum[8];
    __shared__ float fW[3][32];        // folded W2@{Wc,Wmu,Wsig}[4:36]
    __shared__ float fB[3];            // folded b2·{Wc,Wmu,Wsig}[4:36]
    // total ~77.6 KB -> 2 blocks/CU (16 waves/CU at VGPR<=128)

    int b = blockIdx.x;
    int t = threadIdx.x;
    int lane = t & 63, wid = t >> 6;
    int beg = b * BCAP_SLOT;
    int cnt = gcursor[b]; if (cnt > BCAP_SLOT) cnt = BCAP_SLOT;

    hist[t] = 0;
    // fold W2 into the three head vectors (runs once, covered by next barrier)
    if (t < 96) {
        int vsel = t >> 5;
        int k = t & 31;
        const float* Wv = (vsel == 0) ? Wc : (vsel == 1) ? Wmu : Wsig;
        float f = 0.0f;
        #pragma unroll
        for (int j = 0; j < 32; j++) f = fmaf(W2[k * 32 + j], Wv[4 + j], f);
        fW[vsel][k] = f;
    } else if (t < 99) {
        int vsel = t - 96;
        const float* Wv = (vsel == 0) ? Wc : (vsel == 1) ? Wmu : Wsig;
        float f = 0.0f;
        #pragma unroll
        for (int j = 0; j < 32; j++) f = fmaf(b2[j], Wv[4 + j], f);
        fB[vsel] = f;
    }
    __syncthreads();

    // phase A: int4 loads = 2 records each; histogram atomic RETURNS rank
    int2 rec[18];
    int rk[18];
    #pragma unroll
    for (int k = 0; k < 9; k++) {
        int s = (k * 512 + t) * 2;
        int4 pp = *(const int4*)(bpay + beg + s);
        rec[2 * k]     = make_int2(pp.x, pp.y);
        rec[2 * k + 1] = make_int2(pp.z, pp.w);
        rk[2 * k]     = (s < cnt)     ? atomicAdd(&hist[(pp.x >> 18) & (NB - 1)], 1) : 0;
        rk[2 * k + 1] = (s + 1 < cnt) ? atomicAdd(&hist[(pp.z >> 18) & (NB - 1)], 1) : 0;
    }
    __syncthreads();

    // phase B: exclusive scan of 512 counters via shfl (2 barriers)
    int hv = hist[t];
    int v = hv;
    #pragma unroll
    for (int off = 1; off < 64; off <<= 1) {
        int u = __shfl_up(v, off, 64);
        if (lane >= off) v += u;
    }
    if (lane == 63) wsum[wid] = v;
    __syncthreads();
    if (wid == 0) {
        int w = (lane < 8) ? wsum[lane] : 0;
        #pragma unroll
        for (int off = 1; off < 8; off <<= 1) {
            int u = __shfl_up(w, off, 64);
            if (lane >= off) w += u;
        }
        if (lane < 8) wsum[lane] = w;
    }
    __syncthreads();
    int wbase = (wid > 0) ? wsum[wid - 1] : 0;
    nbeg[t] = wbase + (v - hv);
    __syncthreads();

    // phase C: ATOMIC-FREE placement from registers into LDS
    #pragma unroll
    for (int k = 0; k < 9; k++) {
        int s = (k * 512 + t) * 2;
        if (s < cnt) {
            int lrow = (rec[2 * k].x >> 18) & (NB - 1);
            srec[nbeg[lrow] + rk[2 * k]] = rec[2 * k];
        }
        if (s + 1 < cnt) {
            int lrow = (rec[2 * k + 1].x >> 18) & (NB - 1);
            srec[nbeg[lrow] + rk[2 * k + 1]] = rec[2 * k + 1];
        }
    }

    // ---- phase C2: degree-sort node->thread assignment (counting sort, 64 bins)
    int bin = min(hv, 63);
    if (t < 64) dhist[t] = 0;
    __syncthreads();                 // also covers phase-C completion
    atomicAdd(&dhist[bin], 1);
    __syncthreads();
    if (wid == 0) {
        int dv = dhist[lane];
        int sv = dv;
        #pragma unroll
        for (int off = 1; off < 64; off <<= 1) {
            int u = __shfl_up(sv, off, 64);
            if (lane >= off) sv += u;
        }
        dhist[lane] = sv - dv;       // exclusive base, becomes cursor
    }
    __syncthreads();
    int pos = atomicAdd(&dhist[bin], 1);
    perm[pos] = t;                   // perm: rank -> node-local-id
    __syncthreads();

    // ---- phase D: gather math, 1 thread per (degree-sorted) node ----
    int tt = perm[t];
    int n = b * NB + tt;
    bool valid = (n < N_NODES);
    int nn = valid ? n : 0;
    int deg = valid ? hist[tt] : 0;
    int s0 = nbeg[tt];

    float4 xr = *(const float4*)(x + 4 * (size_t)nn);

    const float2v* W1v = (const float2v*)W1;   // [9][16]
    const float2v* b1v = (const float2v*)b1;

    // hoist row-terms: arow = b1 + xr @ W1[0:4]  (edge-invariant)
    float2v arow[16];
    #pragma unroll
    for (int k2 = 0; k2 < 16; k2++) {
        float2v a = b1v[k2];
        a = pk_fma(xr.x, W1v[0 * 16 + k2], a);
        a = pk_fma(xr.y, W1v[1 * 16 + k2], a);
        a = pk_fma(xr.z, W1v[2 * 16 + k2], a);
        a = pk_fma(xr.w, W1v[3 * 16 + k2], a);
        arow[k2] = a;
    }

    // S = sum over edges of relu(in @ W1 + b1)
    float2v acc2[16];
    #pragma unroll
    for (int j2 = 0; j2 < 16; j2++) { float2v z = {0.f, 0.f}; acc2[j2] = z; }

    // --- software pipeline: recs (LDS) + xc (global) one chunk ahead ---
    float mk0[4], ev0[4];
    float4 xc0[4];
    #pragma unroll
    for (int j = 0; j < 4; j++) {
        bool ok = j < deg;
        int idx = ok ? (s0 + j) : 0;
        int2 rr = srec[idx];
        mk0[j] = ok ? 1.0f : 0.0f;
        int col = ok ? (rr.x & 0x3FFFF) : 0;
        ev0[j] = ok ? __int_as_float(rr.y) : 0.0f;
        xc0[j] = *(const float4*)(x + 4 * (size_t)col);
    }

    for (int c = 0; c < deg; c += 4) {
        int c1 = c + 4;
        float mk1[4], ev1[4];
        float4 xc1[4];
        #pragma unroll
        for (int j = 0; j < 4; j++) {
            bool ok = (c1 + j) < deg;
            int idx = ok ? (s0 + c1 + j) : 0;
            int2 rr = srec[idx];
            mk1[j] = ok ? 1.0f : 0.0f;
            int col = ok ? (rr.x & 0x3FFFF) : 0;
            ev1[j] = ok ? __int_as_float(rr.y) : 0.0f;
            xc1[j] = *(const float4*)(x + 4 * (size_t)col);
        }

        // layer-1 column-terms; fused relu + mask*accumulate
        #pragma unroll
        for (int k2 = 0; k2 < 16; k2++) {
            float2v w4 = W1v[4 * 16 + k2];
            float2v w5 = W1v[5 * 16 + k2];
            float2v w6 = W1v[6 * 16 + k2];
            float2v w7 = W1v[7 * 16 + k2];
            float2v w8 = W1v[8 * 16 + k2];
            #pragma unroll
            for (int j = 0; j < 4; j++) {
                float2v a = arow[k2];
                a = pk_fma(xc0[j].x, w4, a);
                a = pk_fma(xc0[j].y, w5, a);
                a = pk_fma(xc0[j].z, w6, a);
                a = pk_fma(xc0[j].w, w7, a);
                a = pk_fma(ev0[j],   w8, a);
                float2v zero = {0.0f, 0.0f};
                a = __builtin_elementwise_max(a, zero);
                float2v mm = {mk0[j], mk0[j]};
                acc2[k2] = __builtin_elementwise_fma(a, mm, acc2[k2]);
            }
        }

        #pragma unroll
        for (int j = 0; j < 4; j++) {
            mk0[j] = mk1[j]; ev0[j] = ev1[j]; xc0[j] = xc1[j];
        }
    }

    float c_val = 0.0f;
    if (valid) {
        // folded epilogue: z = bias + xr·w[0:4] + deg·fB + S·fW
        float* accf = (float*)acc2;
        float fdeg = (float)deg;

        float zc = fmaf(fdeg, fB[0], bc[0]);
        zc = fmaf(xr.x, Wc[0], zc);
        zc = fmaf(xr.y, Wc[1], zc);
        zc = fmaf(xr.z, Wc[2], zc);
        zc = fmaf(xr.w, Wc[3], zc);
        #pragma unroll
        for (int j = 0; j < 32; j++) zc = fmaf(accf[j], fW[0][j], zc);
        c_val = softplus_f(zc + 1e-10f);

        int g = n / NN;
        int i = n - g * NN;
        out[(size_t)g * OUT_COLS + i] = c_val;   // unnormalized; div rescales

        if (i >= NN - NF) {
            float zm = fmaf(fdeg, fB[1], bmu[0]);
            float zs = fmaf(fdeg, fB[2], bsig[0]);
            zm = fmaf(xr.x, Wmu[0], zm);   zs = fmaf(xr.x, Wsig[0], zs);
            zm = fmaf(xr.y, Wmu[1], zm);   zs = fmaf(xr.y, Wsig[1], zs);
            zm = fmaf(xr.z, Wmu[2], zm);   zs = fmaf(xr.z, Wsig[2], zs);
            zm = fmaf(xr.w, Wmu[3], zm);   zs = fmaf(xr.w, Wsig[3], zs);
            #pragma unroll
            for (int j = 0; j < 32; j++) {
                zm = fmaf(accf[j], fW[1][j], zm);
                zs = fmaf(accf[j], fW[2][j], zs);
            }
            float alpha = softplus_f(zm + 1e-20f) + 1e-20f;
            float beta  = softplus_f(zs + 1e-20f) + 1e-20f;
            int k = i - (NN - NF);
            out[(size_t)g * OUT_COLS + NN + k] = alpha / (alpha + beta) * high[k];
        }
    }

    // block partial sum of conc -> single atomic
    float s = c_val;
    #pragma unroll
    for (int off = 32; off > 0; off >>= 1) s += __shfl_down(s, off, 64);
    if (lane == 0) bsum[wid] = s;
    __syncthreads();
    if (t == 0) {
        float tt2 = 0.0f;
        #pragma unroll
        for (int j = 0; j < 8; j++) tt2 += bsum[j];
        atomicAdd(sum_out, tt2);
    }
}

// ---- P4: in-place normalization of inventory columns ----
__global__ __launch_bounds__(256) void div_kernel(
    const float* __restrict__ sum_in, float* __restrict__ out)
{
    int n = blockIdx.x * 256 + threadIdx.x;
    if (n >= N_NODES) return;
    float inv = 1.0f / (*sum_in + 1e-20f);
    int g = n / NN;
    int i = n - g * NN;
    out[(size_t)g * OUT_COLS + i] *= inv;
}

extern "C" void kernel_launch(void* const* d_in, const int* in_sizes, int n_in,
                              void* d_out, int out_size, void* d_ws, size_t ws_size,
                              hipStream_t stream)
{
    const float* x    = (const float*)d_in[0];
    const int*   ei   = (const int*)d_in[1];
    const float* ea   = (const float*)d_in[2];
    const float* high = (const float*)d_in[3];
    const float* W1   = (const float*)d_in[4];
    const float* b1   = (const float*)d_in[5];
    const float* W2   = (const float*)d_in[6];
    const float* b2   = (const float*)d_in[7];
    const float* Wc   = (const float*)d_in[8];
    const float* bc   = (const float*)d_in[9];
    const float* Wmu  = (const float*)d_in[10];
    const float* bmu  = (const float*)d_in[11];
    const float* Wsig = (const float*)d_in[12];
    const float* bsig = (const float*)d_in[13];
    float* out = (float*)d_out;

    char* ws = (char*)d_ws;
    int2*  bpay    = (int2*)ws;                    // 489*8832*8 = 34,550,784 B
    // NOTE: bucket_kernel's vectorized phase A may over-read up to ~3 KB past
    // bpay; the 4 KB scratch below absorbs it (same allocation, initialized).
    int*   gcursor = (int*)(ws + 34550784);        // 2048 B (489 used)
    float* ssum    = (float*)(ws + 34552832);      // 4 B
    // + padding to 34555904 implicitly available in ws

    hipMemsetAsync(gcursor, 0, 2052, stream);      // gcursor + ssum

    part_kernel<<<NPBLK, 1024, 0, stream>>>(ei, ea, gcursor, bpay);
    bucket_kernel<<<NBKT, 512, 0, stream>>>(
        bpay, gcursor, x, W1, b1, W2, b2, Wc, bc, Wmu, bmu, Wsig, bsig,
        high, ssum, out);
    div_kernel<<<(N_NODES + 255) / 256, 256, 0, stream>>>(ssum, out);
}

// Round 6
// 185.376 us; speedup vs baseline: 1.0849x; 1.0849x over previous
//
#include <hip/hip_runtime.h>

#define N_NODES 250000
#define N_EDGES 4000000
#define HID 32
#define NN 50
#define NF 3
#define OUT_COLS (NN + NF)   // 53

#define NB 512                                    // nodes per bucket
#define NBKT ((N_NODES + NB - 1) / NB)            // 489 buckets
#define PCHUNK 4096                               // edges per partition block
#define NPBLK ((N_EDGES + PCHUNK - 1) / PCHUNK)   // 977
#define BCAP_SLOT 8832                            // bucket capacity (mean 8192 + 7 sigma)

typedef float float2v __attribute__((ext_vector_type(2)));

__device__ __forceinline__ float softplus_f(float v) {
    return fmaxf(v, 0.0f) + log1pf(expf(-fabsf(v)));
}

__device__ __forceinline__ float2v pk_fma(float a, float2v b, float2v c) {
    float2v av = {a, a};
    return __builtin_elementwise_fma(av, b, c);
}

// ---- P1: partition edges into fixed-capacity bucket regions ----
// record: w0 = col | (lrow<<18)  (col<2^18, lrow<2^9), w1 = attr bits
// LDS-staged version (round-5 post-mortem: direct 8B scatter caused
// partial-line HBM writebacks, +13 µs — bucket-contiguous runs are the
// point of the staging). CHUNK halved 8192->4096 so LDS ~42 KB -> 
// 2 blocks/CU = 32 waves = 100% occupancy (was 81.6 KB -> 1 block, 50%).
// Write runs avg 4096/489 ~ 8.4 edges = 67 B, still near line-sized.
// Placement is ATOMIC-FREE: pass-1 histogram atomicAdd returns rank.
__global__ __launch_bounds__(1024, 8) void part_kernel(
    const int* __restrict__ ei, const float* __restrict__ ea,
    int* __restrict__ gcursor, int2* __restrict__ bpay)
{
    __shared__ int2 srec[PCHUNK];            // 32 KB — bucket-major slots
    __shared__ int hist[NBKT];               // 1956 B
    __shared__ int excl[NBKT];
    __shared__ int gbase[NBKT];
    __shared__ unsigned char bkt[PCHUNK];    // 4 KB (low 8 bits of bucket id)
    __shared__ int wsum[16];
    // total ~42 KB -> 2 blocks/CU (wave-cap bound), 100% occupancy

    int t = threadIdx.x;
    int lane = t & 63, wid = t >> 6;
    int cbb = blockIdx.x * PCHUNK;
    int cnt = N_EDGES - cbb; if (cnt > PCHUNK) cnt = PCHUNK;

    for (int i = t; i < NBKT; i += 1024) hist[i] = 0;
    __syncthreads();

    // pass 1: int4 row loads (4 edges/thread); histogram atomic RETURNS rank
    int e0 = cbb + t * 4;
    int r[4], rk[4];
    bool full = (e0 + 4 <= N_EDGES);
    if (full) {
        int4 ra = *(const int4*)(ei + e0);
        r[0] = ra.x; r[1] = ra.y; r[2] = ra.z; r[3] = ra.w;
    } else {
        #pragma unroll
        for (int j = 0; j < 4; j++) r[j] = (e0 + j < N_EDGES) ? ei[e0 + j] : 0;
    }
    #pragma unroll
    for (int j = 0; j < 4; j++)
        rk[j] = (e0 + j < N_EDGES) ? atomicAdd(&hist[r[j] >> 9], 1) : 0;
    __syncthreads();

    // scan 489 counters via shfl (2 barriers)
    int hv = (t < NBKT) ? hist[t] : 0;
    int v = hv;
    #pragma unroll
    for (int off = 1; off < 64; off <<= 1) {
        int u = __shfl_up(v, off, 64);
        if (lane >= off) v += u;
    }
    if (lane == 63) wsum[wid] = v;
    __syncthreads();
    if (wid == 0) {
        int w = (lane < 16) ? wsum[lane] : 0;
        #pragma unroll
        for (int off = 1; off < 16; off <<= 1) {
            int u = __shfl_up(w, off, 64);
            if (lane >= off) w += u;
        }
        if (lane < 16) wsum[lane] = w;
    }
    __syncthreads();
    int wbase = (wid > 0) ? wsum[wid - 1] : 0;
    int myExcl = wbase + (v - hv);
    if (t < NBKT) {
        excl[t] = myExcl;
        int base = 0;
        if (hv > 0) base = atomicAdd(&gcursor[t], hv);
        gbase[t] = t * BCAP_SLOT + base;
    }
    __syncthreads();

    // pass 2: int4/float4 col/attr loads; ATOMIC-FREE bucket-major placement
    if (full) {
        int4 ca = *(const int4*)(ei + N_EDGES + e0);
        float4 aa = *(const float4*)(ea + e0);
        int c[4] = {ca.x, ca.y, ca.z, ca.w};
        float a[4] = {aa.x, aa.y, aa.z, aa.w};
        #pragma unroll
        for (int j = 0; j < 4; j++) {
            int bb = r[j] >> 9;
            int lrow = r[j] & (NB - 1);
            int slot = excl[bb] + rk[j];
            srec[slot] = make_int2(c[j] | (lrow << 18), __float_as_int(a[j]));
            bkt[slot] = (unsigned char)(bb & 0xFF);
        }
    } else {
        #pragma unroll
        for (int j = 0; j < 4; j++) {
            if (e0 + j < N_EDGES) {
                int bb = r[j] >> 9;
                int lrow = r[j] & (NB - 1);
                int col  = ei[N_EDGES + e0 + j];
                float at = ea[e0 + j];
                int slot = excl[bb] + rk[j];
                srec[slot] = make_int2(col | (lrow << 18), __float_as_int(at));
                bkt[slot] = (unsigned char)(bb & 0xFF);
            }
        }
    }
    __syncthreads();

    // pass 3: emit bucket-contiguous runs (sequential LDS read, coalesced write)
    // bucket id recovered from uchar low-bits + monotone excl[] (NBKT < 512)
    for (int s = t; s < cnt; s += 1024) {
        int2 rec = srec[s];
        int c1 = bkt[s];
        int c2 = c1 + 256;
        int bb = (c2 < NBKT && excl[c2] <= s) ? c2 : c1;
        int gpos = gbase[bb] + (s - excl[bb]);
        if (gpos < (bb + 1) * BCAP_SLOT)        // overflow clamp (never in practice)
            bpay[gpos] = rec;
    }
}

// ---- P2+P3 fused: per-bucket counting sort into LDS + gather math ----
// 489 blocks x 512 threads; 1 thread per node. Sorted records never touch
// global memory. Phase A loads 2 records per int4 (guarded over-read lands
// in the ws scratch area past bpay -- safe by workspace layout). Phase C
// placement is atomic-free (rank from phase A's histogram atomic). Phase D
// is degree-sorted for wave-uniform edge counts. Epilogue folds W2 into
// Wc/Wmu/Wsig per block: (S@W2)·w == S·(W2@w).
// NOTE: no grid-wide spin barrier (round-3 post-mortem: 20 ms pathology).
__global__ __launch_bounds__(512, 4) void bucket_kernel(
    const int2* __restrict__ bpay, const int* __restrict__ gcursor,
    const float* __restrict__ x,
    const float* __restrict__ W1, const float* __restrict__ b1,
    const float* __restrict__ W2, const float* __restrict__ b2,
    const float* __restrict__ Wc, const float* __restrict__ bc,
    const float* __restrict__ Wmu, const float* __restrict__ bmu,
    const float* __restrict__ Wsig, const float* __restrict__ bsig,
    const float* __restrict__ high,
    float* __restrict__ sum_out, float* __restrict__ out)
{
    __shared__ int2 srec[BCAP_SLOT];   // 69 KB — node-sorted records
    __shared__ int hist[NB];           // 2 KB (per-node degree)
    __shared__ int nbeg[NB];           // 2 KB (per-node start, immutable)
    __shared__ int perm[NB];           // 2 KB (degree-sorted rank -> node)
    __shared__ int dhist[64];          // 256 B (degree bins -> cursor)
    __shared__ int wsum[8];
    __shared__ float bsum[8];
    __shared__ float fW[3][32];        // folded W2@{Wc,Wmu,Wsig}[4:36]
    __shared__ float fB[3];            // folded b2·{Wc,Wmu,Wsig}[4:36]
    // total ~77.6 KB -> 2 blocks/CU (16 waves/CU at VGPR<=128)

    int b = blockIdx.x;
    int t = threadIdx.x;
    int lane = t & 63, wid = t >> 6;
    int beg = b * BCAP_SLOT;
    int cnt = gcursor[b]; if (cnt > BCAP_SLOT) cnt = BCAP_SLOT;

    hist[t] = 0;
    // fold W2 into the three head vectors (runs once, covered by next barrier)
    if (t < 96) {
        int vsel = t >> 5;
        int k = t & 31;
        const float* Wv = (vsel == 0) ? Wc : (vsel == 1) ? Wmu : Wsig;
        float f = 0.0f;
        #pragma unroll
        for (int j = 0; j < 32; j++) f = fmaf(W2[k * 32 + j], Wv[4 + j], f);
        fW[vsel][k] = f;
    } else if (t < 99) {
        int vsel = t - 96;
        const float* Wv = (vsel == 0) ? Wc : (vsel == 1) ? Wmu : Wsig;
        float f = 0.0f;
        #pragma unroll
        for (int j = 0; j < 32; j++) f = fmaf(b2[j], Wv[4 + j], f);
        fB[vsel] = f;
    }
    __syncthreads();

    // phase A: int4 loads = 2 records each; histogram atomic RETURNS rank
    int2 rec[18];
    int rk[18];
    #pragma unroll
    for (int k = 0; k < 9; k++) {
        int s = (k * 512 + t) * 2;
        int4 pp = *(const int4*)(bpay + beg + s);
        rec[2 * k]     = make_int2(pp.x, pp.y);
        rec[2 * k + 1] = make_int2(pp.z, pp.w);
        rk[2 * k]     = (s < cnt)     ? atomicAdd(&hist[(pp.x >> 18) & (NB - 1)], 1) : 0;
        rk[2 * k + 1] = (s + 1 < cnt) ? atomicAdd(&hist[(pp.z >> 18) & (NB - 1)], 1) : 0;
    }
    __syncthreads();

    // phase B: exclusive scan of 512 counters via shfl (2 barriers)
    int hv = hist[t];
    int v = hv;
    #pragma unroll
    for (int off = 1; off < 64; off <<= 1) {
        int u = __shfl_up(v, off, 64);
        if (lane >= off) v += u;
    }
    if (lane == 63) wsum[wid] = v;
    __syncthreads();
    if (wid == 0) {
        int w = (lane < 8) ? wsum[lane] : 0;
        #pragma unroll
        for (int off = 1; off < 8; off <<= 1) {
            int u = __shfl_up(w, off, 64);
            if (lane >= off) w += u;
        }
        if (lane < 8) wsum[lane] = w;
    }
    __syncthreads();
    int wbase = (wid > 0) ? wsum[wid - 1] : 0;
    nbeg[t] = wbase + (v - hv);
    __syncthreads();

    // phase C: ATOMIC-FREE placement from registers into LDS
    #pragma unroll
    for (int k = 0; k < 9; k++) {
        int s = (k * 512 + t) * 2;
        if (s < cnt) {
            int lrow = (rec[2 * k].x >> 18) & (NB - 1);
            srec[nbeg[lrow] + rk[2 * k]] = rec[2 * k];
        }
        if (s + 1 < cnt) {
            int lrow = (rec[2 * k + 1].x >> 18) & (NB - 1);
            srec[nbeg[lrow] + rk[2 * k + 1]] = rec[2 * k + 1];
        }
    }

    // ---- phase C2: degree-sort node->thread assignment (counting sort, 64 bins)
    int bin = min(hv, 63);
    if (t < 64) dhist[t] = 0;
    __syncthreads();                 // also covers phase-C completion
    atomicAdd(&dhist[bin], 1);
    __syncthreads();
    if (wid == 0) {
        int dv = dhist[lane];
        int sv = dv;
        #pragma unroll
        for (int off = 1; off < 64; off <<= 1) {
            int u = __shfl_up(sv, off, 64);
            if (lane >= off) sv += u;
        }
        dhist[lane] = sv - dv;       // exclusive base, becomes cursor
    }
    __syncthreads();
    int pos = atomicAdd(&dhist[bin], 1);
    perm[pos] = t;                   // perm: rank -> node-local-id
    __syncthreads();

    // ---- phase D: gather math, 1 thread per (degree-sorted) node ----
    int tt = perm[t];
    int n = b * NB + tt;
    bool valid = (n < N_NODES);
    int nn = valid ? n : 0;
    int deg = valid ? hist[tt] : 0;
    int s0 = nbeg[tt];

    float4 xr = *(const float4*)(x + 4 * (size_t)nn);

    const float2v* W1v = (const float2v*)W1;   // [9][16]
    const float2v* b1v = (const float2v*)b1;

    // hoist row-terms: arow = b1 + xr @ W1[0:4]  (edge-invariant)
    float2v arow[16];
    #pragma unroll
    for (int k2 = 0; k2 < 16; k2++) {
        float2v a = b1v[k2];
        a = pk_fma(xr.x, W1v[0 * 16 + k2], a);
        a = pk_fma(xr.y, W1v[1 * 16 + k2], a);
        a = pk_fma(xr.z, W1v[2 * 16 + k2], a);
        a = pk_fma(xr.w, W1v[3 * 16 + k2], a);
        arow[k2] = a;
    }

    // S = sum over edges of relu(in @ W1 + b1)
    float2v acc2[16];
    #pragma unroll
    for (int j2 = 0; j2 < 16; j2++) { float2v z = {0.f, 0.f}; acc2[j2] = z; }

    // --- software pipeline: recs (LDS) + xc (global) one chunk ahead ---
    float mk0[4], ev0[4];
    float4 xc0[4];
    #pragma unroll
    for (int j = 0; j < 4; j++) {
        bool ok = j < deg;
        int idx = ok ? (s0 + j) : 0;
        int2 rr = srec[idx];
        mk0[j] = ok ? 1.0f : 0.0f;
        int col = ok ? (rr.x & 0x3FFFF) : 0;
        ev0[j] = ok ? __int_as_float(rr.y) : 0.0f;
        xc0[j] = *(const float4*)(x + 4 * (size_t)col);
    }

    for (int c = 0; c < deg; c += 4) {
        int c1 = c + 4;
        float mk1[4], ev1[4];
        float4 xc1[4];
        #pragma unroll
        for (int j = 0; j < 4; j++) {
            bool ok = (c1 + j) < deg;
            int idx = ok ? (s0 + c1 + j) : 0;
            int2 rr = srec[idx];
            mk1[j] = ok ? 1.0f : 0.0f;
            int col = ok ? (rr.x & 0x3FFFF) : 0;
            ev1[j] = ok ? __int_as_float(rr.y) : 0.0f;
            xc1[j] = *(const float4*)(x + 4 * (size_t)col);
        }

        // layer-1 column-terms; fused relu + mask*accumulate
        #pragma unroll
        for (int k2 = 0; k2 < 16; k2++) {
            float2v w4 = W1v[4 * 16 + k2];
            float2v w5 = W1v[5 * 16 + k2];
            float2v w6 = W1v[6 * 16 + k2];
            float2v w7 = W1v[7 * 16 + k2];
            float2v w8 = W1v[8 * 16 + k2];
            #pragma unroll
            for (int j = 0; j < 4; j++) {
                float2v a = arow[k2];
                a = pk_fma(xc0[j].x, w4, a);
                a = pk_fma(xc0[j].y, w5, a);
                a = pk_fma(xc0[j].z, w6, a);
                a = pk_fma(xc0[j].w, w7, a);
                a = pk_fma(ev0[j],   w8, a);
                float2v zero = {0.0f, 0.0f};
                a = __builtin_elementwise_max(a, zero);
                float2v mm = {mk0[j], mk0[j]};
                acc2[k2] = __builtin_elementwise_fma(a, mm, acc2[k2]);
            }
        }

        #pragma unroll
        for (int j = 0; j < 4; j++) {
            mk0[j] = mk1[j]; ev0[j] = ev1[j]; xc0[j] = xc1[j];
        }
    }

    float c_val = 0.0f;
    if (valid) {
        // folded epilogue: z = bias + xr·w[0:4] + deg·fB + S·fW
        float* accf = (float*)acc2;
        float fdeg = (float)deg;

        float zc = fmaf(fdeg, fB[0], bc[0]);
        zc = fmaf(xr.x, Wc[0], zc);
        zc = fmaf(xr.y, Wc[1], zc);
        zc = fmaf(xr.z, Wc[2], zc);
        zc = fmaf(xr.w, Wc[3], zc);
        #pragma unroll
        for (int j = 0; j < 32; j++) zc = fmaf(accf[j], fW[0][j], zc);
        c_val = softplus_f(zc + 1e-10f);

        int g = n / NN;
        int i = n - g * NN;
        out[(size_t)g * OUT_COLS + i] = c_val;   // unnormalized; div rescales

        if (i >= NN - NF) {
            float zm = fmaf(fdeg, fB[1], bmu[0]);
            float zs = fmaf(fdeg, fB[2], bsig[0]);
            zm = fmaf(xr.x, Wmu[0], zm);   zs = fmaf(xr.x, Wsig[0], zs);
            zm = fmaf(xr.y, Wmu[1], zm);   zs = fmaf(xr.y, Wsig[1], zs);
            zm = fmaf(xr.z, Wmu[2], zm);   zs = fmaf(xr.z, Wsig[2], zs);
            zm = fmaf(xr.w, Wmu[3], zm);   zs = fmaf(xr.w, Wsig[3], zs);
            #pragma unroll
            for (int j = 0; j < 32; j++) {
                zm = fmaf(accf[j], fW[1][j], zm);
                zs = fmaf(accf[j], fW[2][j], zs);
            }
            float alpha = softplus_f(zm + 1e-20f) + 1e-20f;
            float beta  = softplus_f(zs + 1e-20f) + 1e-20f;
            int k = i - (NN - NF);
            out[(size_t)g * OUT_COLS + NN + k] = alpha / (alpha + beta) * high[k];
        }
    }

    // block partial sum of conc -> single atomic
    float s = c_val;
    #pragma unroll
    for (int off = 32; off > 0; off >>= 1) s += __shfl_down(s, off, 64);
    if (lane == 0) bsum[wid] = s;
    __syncthreads();
    if (t == 0) {
        float tt2 = 0.0f;
        #pragma unroll
        for (int j = 0; j < 8; j++) tt2 += bsum[j];
        atomicAdd(sum_out, tt2);
    }
}

// ---- P4: in-place normalization of inventory columns ----
__global__ __launch_bounds__(256) void div_kernel(
    const float* __restrict__ sum_in, float* __restrict__ out)
{
    int n = blockIdx.x * 256 + threadIdx.x;
    if (n >= N_NODES) return;
    float inv = 1.0f / (*sum_in + 1e-20f);
    int g = n / NN;
    int i = n - g * NN;
    out[(size_t)g * OUT_COLS + i] *= inv;
}

extern "C" void kernel_launch(void* const* d_in, const int* in_sizes, int n_in,
                              void* d_out, int out_size, void* d_ws, size_t ws_size,
                              hipStream_t stream)
{
    const float* x    = (const float*)d_in[0];
    const int*   ei   = (const int*)d_in[1];
    const float* ea   = (const float*)d_in[2];
    const float* high = (const float*)d_in[3];
    const float* W1   = (const float*)d_in[4];
    const float* b1   = (const float*)d_in[5];
    const float* W2   = (const float*)d_in[6];
    const float* b2   = (const float*)d_in[7];
    const float* Wc   = (const float*)d_in[8];
    const float* bc   = (const float*)d_in[9];
    const float* Wmu  = (const float*)d_in[10];
    const float* bmu  = (const float*)d_in[11];
    const float* Wsig = (const float*)d_in[12];
    const float* bsig = (const float*)d_in[13];
    float* out = (float*)d_out;

    char* ws = (char*)d_ws;
    int2*  bpay    = (int2*)ws;                    // 489*8832*8 = 34,550,784 B
    // NOTE: bucket_kernel's vectorized phase A may over-read up to ~3 KB past
    // bpay; the scratch below absorbs it (same allocation, initialized).
    int*   gcursor = (int*)(ws + 34550784);        // 2048 B (489 used)
    float* ssum    = (float*)(ws + 34552832);      // 4 B
    // + padding implicitly available in ws

    hipMemsetAsync(gcursor, 0, 2052, stream);      // gcursor + ssum

    part_kernel<<<NPBLK, 1024, 0, stream>>>(ei, ea, gcursor, bpay);
    bucket_kernel<<<NBKT, 512, 0, stream>>>(
        bpay, gcursor, x, W1, b1, W2, b2, Wc, bc, Wmu, bmu, Wsig, bsig,
        high, ssum, out);
    div_kernel<<<(N_NODES + 255) / 256, 256, 0, stream>>>(ssum, out);
}